// Round 10
// baseline (434.861 us; speedup 1.0000x reference)
//
#include <hip/hip_runtime.h>
#include <hip/hip_bf16.h>

typedef __hip_bfloat16 bf16;
using bf16x8 = __attribute__((ext_vector_type(8))) short;
using bf16x4 = __attribute__((ext_vector_type(4))) short;
using f32x4  = __attribute__((ext_vector_type(4))) float;

#define D_MODEL 1024
#define SEQ     2048
#define NTOK    4096
#define NHEAD   16
#define DHEAD   64

__device__ inline f32x4 mfma16(bf16x8 a, bf16x8 b, f32x4 c) {
  return __builtin_amdgcn_mfma_f32_16x16x32_bf16(a, b, c, 0, 0, 0);
}

// 16x16x16 bf16 MFMA (K=16): A/B = 4 bf16 (2 VGPRs), k = quad*4+j
__device__ inline f32x4 mfma16k16(bf16x4 a, bf16x4 b, f32x4 c) {
#if __has_builtin(__builtin_amdgcn_mfma_f32_16x16x16bf16_1k)
  return __builtin_amdgcn_mfma_f32_16x16x16bf16_1k(a, b, c, 0, 0, 0);
#else
  f32x4 d;
  asm("v_mfma_f32_16x16x16_bf16 %0, %1, %2, %3" : "=v"(d) : "v"(a), "v"(b), "v"(c));
  return d;
#endif
}

// async global->LDS, 16B per lane, dest = wave-uniform base + lane*16
__device__ inline void glds16(const void* g, void* l) {
  __builtin_amdgcn_global_load_lds(
      (const __attribute__((address_space(1))) unsigned int*)g,
      (__attribute__((address_space(3))) unsigned int*)l, 16, 0, 0);
}

#define MEMFENCE() asm volatile("" ::: "memory")
#define LGKM0_BARRIER()                                        \
  asm volatile("s_waitcnt lgkmcnt(0)" ::: "memory");           \
  asm volatile("s_barrier" ::: "memory")

// ---------------- fp32 -> bf16 convert, all 4 weights in one launch ----------
__global__ __launch_bounds__(256) void f2bf4_kernel(const float* __restrict__ s0,
                                                    const float* __restrict__ s1,
                                                    const float* __restrict__ s2,
                                                    const float* __restrict__ s3,
                                                    bf16* __restrict__ dst) {
  const size_t M1 = (size_t)D_MODEL * D_MODEL;
  size_t i = ((size_t)blockIdx.x * 256 + threadIdx.x) * 4;
  const float* s; size_t off;
  if (i < 3 * M1)      { s = s0; off = i; }
  else if (i < 4 * M1) { s = s1; off = i - 3 * M1; }
  else if (i < 8 * M1) { s = s2; off = i - 4 * M1; }
  else                 { s = s3; off = i - 8 * M1; }
  float4 v = *(const float4*)(s + off);
  dst[i + 0] = __float2bfloat16(v.x);
  dst[i + 1] = __float2bfloat16(v.y);
  dst[i + 2] = __float2bfloat16(v.z);
  dst[i + 3] = __float2bfloat16(v.w);
}

// ---------------- layernorm fp32 -> bf16 ----------------
__global__ __launch_bounds__(256) void ln_kernel(const float* __restrict__ x,
                                                 const float* __restrict__ g,
                                                 const float* __restrict__ bta,
                                                 bf16* __restrict__ out) {
  int row = blockIdx.x;
  int tid = threadIdx.x;
  const float* xr = x + (size_t)row * D_MODEL;
  float4 v = *(const float4*)(xr + tid * 4);
  float s  = v.x + v.y + v.z + v.w;
  float s2 = v.x * v.x + v.y * v.y + v.z * v.z + v.w * v.w;
  for (int o = 32; o > 0; o >>= 1) {
    s  += __shfl_down(s, o);
    s2 += __shfl_down(s2, o);
  }
  __shared__ float red[8];
  int wave = tid >> 6, lane = tid & 63;
  if (lane == 0) { red[wave] = s; red[4 + wave] = s2; }
  __syncthreads();
  s  = red[0] + red[1] + red[2] + red[3];
  s2 = red[4] + red[5] + red[6] + red[7];
  float mu  = s * (1.f / D_MODEL);
  float var = s2 * (1.f / D_MODEL) - mu * mu;
  float rs  = rsqrtf(var + 1e-5f);
  float4 gv = *(const float4*)(g + tid * 4);
  float4 bv = *(const float4*)(bta + tid * 4);
  bf16* orow = out + (size_t)row * D_MODEL + tid * 4;
  orow[0] = __float2bfloat16((v.x - mu) * rs * gv.x + bv.x);
  orow[1] = __float2bfloat16((v.y - mu) * rs * gv.y + bv.y);
  orow[2] = __float2bfloat16((v.z - mu) * rs * gv.z + bv.z);
  orow[3] = __float2bfloat16((v.w - mu) * rs * gv.w + bv.w);
}

// ---------------- epilogue helper ----------------
#define EP_BIAS_BF16      0
#define EP_BIAS_GELU_BF16 1
#define EP_BIAS_RES_F32   2

template <int EP>
__device__ inline void ep_store(void* out, const float* res, size_t off, float v) {
  if (EP == EP_BIAS_BF16) {
    ((bf16*)out)[off] = __float2bfloat16(v);
  } else if (EP == EP_BIAS_GELU_BF16) {
    float u = 0.7978845608f * (v + 0.044715f * v * v * v);
    float gl = v / (1.0f + __expf(-2.0f * u));  // 0.5v(1+tanh(u)) == v*sigmoid(2u)
    ((bf16*)out)[off] = __float2bfloat16(gl);
  } else {
    ((float*)out)[off] = res[off] + v;
  }
}

// ---------------- NT GEMM 128x128 v2: never-drain pipeline ----------------
// A direct global->register (double-buffered, no LDS); B via glds16 into
// LDS double-buffer. One raw barrier per iter; vmcnt(8) waits only the glds
// issued a full compute-phase earlier — staging latency fully hidden.
template <int EP>
__global__ __launch_bounds__(256, 3) void gemm_nt(const bf16* __restrict__ A_,
                                                  const bf16* __restrict__ W_,
                                                  const float* __restrict__ bias,
                                                  const float* res, void* out,
                                                  int M, int N, int K) {
  __shared__ short sB[2][128 * 64];
  const short* A = (const short*)A_;
  const short* W = (const short*)W_;
  int tid  = threadIdx.x;
  int wave = tid >> 6, lane = tid & 63;
  int quad = lane >> 4, l16 = lane & 15;
  int wm = (wave >> 1) * 64, wn = (wave & 1) * 64;
  int bm = blockIdx.x * 128, bn = blockIdx.y * 128;

  int rl = lane >> 3, cz = (lane & 7) ^ rl;
  const short* bp[4];
#pragma unroll
  for (int i = 0; i < 4; i++)
    bp[i] = W + (size_t)(bn + (wave * 4 + i) * 8 + rl) * K + cz * 8;
  const short* ar[4];
#pragma unroll
  for (int t = 0; t < 4; t++)
    ar[t] = A + (size_t)(bm + wm + t * 16 + l16) * K + quad * 8;

  // prologue: glds B(0) FIRST (vmcnt(8) below assumes glds are the oldest)
#pragma unroll
  for (int i = 0; i < 4; i++)
    glds16(bp[i], (char*)sB[0] + (wave * 4 + i) * 1024);
  MEMFENCE();
  bf16x8 acur[4][2], anext[4][2];
#pragma unroll
  for (int t = 0; t < 4; t++)
#pragma unroll
    for (int kk = 0; kk < 2; kk++)
      acur[t][kk] = *(const bf16x8*)(ar[t] + kk * 32);

  f32x4 acc[4][4] = {};
  int niter = K >> 6;

  for (int it = 0; it < niter; it++) {
    int k0 = it << 6;
    // glds B(it) landed (4 oldest of the 12 outstanding); A(it) may still fly
    asm volatile("s_waitcnt vmcnt(8)" ::: "memory");
    LGKM0_BARRIER();   // B(it) visible to all; all waves done reading buf (it+1)&1

    bool more = (it + 1 < niter);
    if (more) {
#pragma unroll
      for (int i = 0; i < 4; i++)
        glds16(bp[i] + k0 + 64, (char*)sB[(it + 1) & 1] + (wave * 4 + i) * 1024);
      MEMFENCE();      // keep glds older than the A loads (vmcnt ordering)
#pragma unroll
      for (int t = 0; t < 4; t++)
#pragma unroll
        for (int kk = 0; kk < 2; kk++)
          anext[t][kk] = *(const bf16x8*)(ar[t] + k0 + 64 + kk * 32);
    }

    const short* sb = sB[it & 1];
#pragma unroll
    for (int kk = 0; kk < 2; kk++) {
      int sw = (((kk * 4 + quad)) ^ (l16 & 7)) * 8;
      bf16x8 bfr[4];
#pragma unroll
      for (int t = 0; t < 4; t++)
        bfr[t] = *(const bf16x8*)&sb[(wn + t * 16 + l16) * 64 + sw];
#pragma unroll
      for (int mt = 0; mt < 4; mt++)
#pragma unroll
        for (int nt = 0; nt < 4; nt++)
          acc[mt][nt] = mfma16(acur[mt][kk], bfr[nt], acc[mt][nt]);
    }
    if (more) {
#pragma unroll
      for (int t = 0; t < 4; t++)
#pragma unroll
        for (int kk = 0; kk < 2; kk++)
          acur[t][kk] = anext[t][kk];
    }
  }

#pragma unroll
  for (int mt = 0; mt < 4; mt++)
#pragma unroll
    for (int nt = 0; nt < 4; nt++) {
      int col = bn + wn + nt * 16 + l16;
      float bs = bias[col];
#pragma unroll
      for (int i = 0; i < 4; i++) {
        int row = bm + wm + mt * 16 + quad * 4 + i;
        ep_store<EP>(out, res, (size_t)row * N + col, acc[mt][nt][i] + bs);
      }
    }
}

// ---------------- NT GEMM 128x64 v2: same pipeline (N=1024 GEMMs) ----------
template <int EP>
__global__ __launch_bounds__(256, 3) void gemm_nt2(const bf16* __restrict__ A_,
                                                   const bf16* __restrict__ W_,
                                                   const float* __restrict__ bias,
                                                   const float* res, void* out,
                                                   int M, int N, int K) {
  __shared__ short sB[2][64 * 64];
  const short* A = (const short*)A_;
  const short* W = (const short*)W_;
  int tid  = threadIdx.x;
  int wave = tid >> 6, lane = tid & 63;
  int quad = lane >> 4, l16 = lane & 15;
  int wm = wave * 32;
  int bm = blockIdx.x * 128, bn = blockIdx.y * 64;

  int rl = lane >> 3, cz = (lane & 7) ^ rl;
  const short* bp[2];
#pragma unroll
  for (int i = 0; i < 2; i++)
    bp[i] = W + (size_t)(bn + (wave * 2 + i) * 8 + rl) * K + cz * 8;
  const short* ar[2];
#pragma unroll
  for (int t = 0; t < 2; t++)
    ar[t] = A + (size_t)(bm + wm + t * 16 + l16) * K + quad * 8;

#pragma unroll
  for (int i = 0; i < 2; i++)
    glds16(bp[i], (char*)sB[0] + (wave * 2 + i) * 1024);
  MEMFENCE();
  bf16x8 acur[2][2], anext[2][2];
#pragma unroll
  for (int t = 0; t < 2; t++)
#pragma unroll
    for (int kk = 0; kk < 2; kk++)
      acur[t][kk] = *(const bf16x8*)(ar[t] + kk * 32);

  f32x4 acc[2][4] = {};
  int niter = K >> 6;

  for (int it = 0; it < niter; it++) {
    int k0 = it << 6;
    asm volatile("s_waitcnt vmcnt(4)" ::: "memory");  // glds B(it) landed
    LGKM0_BARRIER();

    bool more = (it + 1 < niter);
    if (more) {
#pragma unroll
      for (int i = 0; i < 2; i++)
        glds16(bp[i] + k0 + 64, (char*)sB[(it + 1) & 1] + (wave * 2 + i) * 1024);
      MEMFENCE();
#pragma unroll
      for (int t = 0; t < 2; t++)
#pragma unroll
        for (int kk = 0; kk < 2; kk++)
          anext[t][kk] = *(const bf16x8*)(ar[t] + k0 + 64 + kk * 32);
    }

    const short* sb = sB[it & 1];
#pragma unroll
    for (int kk = 0; kk < 2; kk++) {
      int sw = (((kk * 4 + quad)) ^ (l16 & 7)) * 8;
      bf16x8 bfr[4];
#pragma unroll
      for (int t = 0; t < 4; t++)
        bfr[t] = *(const bf16x8*)&sb[(t * 16 + l16) * 64 + sw];
#pragma unroll
      for (int mt = 0; mt < 2; mt++)
#pragma unroll
        for (int nt = 0; nt < 4; nt++)
          acc[mt][nt] = mfma16(acur[mt][kk], bfr[nt], acc[mt][nt]);
    }
    if (more) {
#pragma unroll
      for (int t = 0; t < 2; t++)
#pragma unroll
        for (int kk = 0; kk < 2; kk++)
          acur[t][kk] = anext[t][kk];
    }
  }

#pragma unroll
  for (int mt = 0; mt < 2; mt++)
#pragma unroll
    for (int nt = 0; nt < 4; nt++) {
      int col = bn + nt * 16 + l16;
      float bs = bias[col];
#pragma unroll
      for (int i = 0; i < 4; i++) {
        int row = bm + wm + mt * 16 + quad * 4 + i;
        ep_store<EP>(out, res, (size_t)row * N + col, acc[mt][nt][i] + bs);
      }
    }
}

// ---------------- flash attention (r7 version verbatim — best measured 66us) -
__global__ __launch_bounds__(256, 2) void attn_kernel(const short* __restrict__ qkvS,
                                                      short* __restrict__ oS) {
  int bh = blockIdx.y;
  int b = bh >> 4, h = bh & 15;
  int iq = blockIdx.x;                  // 0..15
  int qa = iq * 64, qb = (31 - iq) * 64;
  int tid = threadIdx.x, wave = tid >> 6, lane = tid & 63;
  int quad = lane >> 4, l16 = lane & 15;
  const int RS = 3 * D_MODEL;
  const short* base = qkvS + (size_t)b * SEQ * RS;
  const int koff = D_MODEL + h * 64, voff = 2 * D_MODEL + h * 64, qoff = h * 64;
  const float c2 = 0.1803368801f;  // log2(e)/8

  __shared__ short sK[64 * 64];
  __shared__ short sV[64 * 64];

  int rl = lane >> 3, cz = (lane & 7) ^ rl;
  int vkr = tid >> 3, vd0 = (tid & 7) * 8;
  int vb7 = tid & 7;
  int kv3 = vkr & 3;
  int c4lo = vkr >> 2, c4hi = c4lo + 8;
  int xpar = (c4lo & 1) << 3;

  int qrA = qa + wave * 16 + l16, qrB = qb + wave * 16 + l16;
  bf16x8 qA0 = *(const bf16x8*)&base[(size_t)qrA * RS + qoff + quad * 8];
  bf16x8 qA1 = *(const bf16x8*)&base[(size_t)qrA * RS + qoff + 32 + quad * 8];
  bf16x8 qB0 = *(const bf16x8*)&base[(size_t)qrB * RS + qoff + quad * 8];
  bf16x8 qB1 = *(const bf16x8*)&base[(size_t)qrB * RS + qoff + 32 + quad * 8];

  f32x4 oA[4] = {}, oB[4] = {};
  float lsA = 0.f, lsB = 0.f;
  int ntile = 32 - iq;

  bf16x8 kc0, kc1, vc0, vc1;
  {
    const short* kp = &base[(size_t)(wave * 16 + rl) * RS + koff + cz * 8];
    kc0 = *(const bf16x8*)kp;
    kc1 = *(const bf16x8*)(kp + (size_t)8 * RS);
    const short* vp = &base[(size_t)vkr * RS + voff + vd0];
    vc0 = *(const bf16x8*)vp;
    vc1 = *(const bf16x8*)(vp + (size_t)32 * RS);
  }

  for (int t = 0; t < ntile; t++) {
    int kv0 = t * 64;
    LGKM0_BARRIER();   // prev tile's LDS reads done (no vmcnt drain)

    bf16x8 kn0, kn1, vn0, vn1;
    bool more = (t + 1 < ntile);
    if (more) {
      int kvn = kv0 + 64;
      const short* kp = &base[(size_t)(kvn + wave * 16 + rl) * RS + koff + cz * 8];
      kn0 = *(const bf16x8*)kp;
      kn1 = *(const bf16x8*)(kp + (size_t)8 * RS);
      const short* vp = &base[(size_t)(kvn + vkr) * RS + voff + vd0];
      vn0 = *(const bf16x8*)vp;
      vn1 = *(const bf16x8*)(vp + (size_t)32 * RS);
    }

    *(bf16x8*)&sK[(wave * 2 + 0) * 512 + lane * 8] = kc0;
    *(bf16x8*)&sK[(wave * 2 + 1) * 512 + lane * 8] = kc1;
#pragma unroll
    for (int j = 0; j < 8; j++)
      sV[c4lo * 256 + (vb7 | ((j << 3) ^ xpar)) * 4 + kv3] = vc0[j];
#pragma unroll
    for (int j = 0; j < 8; j++)
      sV[c4hi * 256 + (vb7 | ((j << 3) ^ xpar)) * 4 + kv3] = vc1[j];

    LGKM0_BARRIER();   // stage visible

    bool doA = (t <= iq);
    int xk = l16 & 7;
    f32x4 stB[4], stA[4];
#pragma unroll
    for (int t16 = 0; t16 < 4; t16++) {
      bf16x8 kf0 = *(const bf16x8*)&sK[(t16 * 16 + l16) * 64 + ((quad ^ xk) * 8)];
      bf16x8 kf1 = *(const bf16x8*)&sK[(t16 * 16 + l16) * 64 + (((quad + 4) ^ xk) * 8)];
      f32x4 z = {};
      z = mfma16(kf0, qB0, z);
      stB[t16] = mfma16(kf1, qB1, z);
      if (doA) {
        f32x4 za = {};
        za = mfma16(kf0, qA0, za);
        stA[t16] = mfma16(kf1, qA1, za);
      }
    }

    auto ptail = [&](const f32x4* st, f32x4* oo, float& ls, bool diag, int qg) {
#pragma unroll
      for (int t16 = 0; t16 < 4; t16++) {
        bf16x4 pf;
        int kvb = kv0 + t16 * 16 + quad * 4;
#pragma unroll
        for (int e = 0; e < 4; e++) {
          float p = exp2f(fminf(st[t16][e] * c2, 30.f));
          if (diag && (kvb + e > qg)) p = 0.f;
          ls += p;
          pf[e] = __builtin_bit_cast(short, __float2bfloat16(p));
        }
        int c4r = t16 * 4 + quad;
        int xr = (c4r & 1) << 3;
#pragma unroll
        for (int dt = 0; dt < 4; dt++) {
          int pr = (dt * 16 + l16) ^ xr;
          bf16x4 vb = *(const bf16x4*)&sV[c4r * 256 + pr * 4];
          oo[dt] = mfma16k16(pf, vb, oo[dt]);
        }
      }
    };

    ptail(stB, oB, lsB, t == ntile - 1, qrB);
    if (doA) ptail(stA, oA, lsA, t == iq, qrA);

    if (more) { kc0 = kn0; kc1 = kn1; vc0 = vn0; vc1 = vn1; }
  }

  auto finish = [&](f32x4* oo, float ls, int q0p) {
    ls += __shfl_xor(ls, 16);
    ls += __shfl_xor(ls, 32);
    float inv[4];
#pragma unroll
    for (int e = 0; e < 4; e++) inv[e] = 1.0f / __shfl(ls, quad * 4 + e);
    int sigbase = ((l16 & 7) << 3) | (l16 >> 3);   // sigma(dt,l16) = sigbase + dt*2
#pragma unroll
    for (int dt = 0; dt < 4; dt++)
#pragma unroll
      for (int e = 0; e < 4; e++) {
        int row = q0p + wave * 16 + quad * 4 + e;
        oS[((size_t)b * SEQ + row) * D_MODEL + qoff + sigbase + dt * 2] =
            __builtin_bit_cast(short, __float2bfloat16(oo[dt][e] * inv[e]));
      }
  };
  finish(oB, lsB, qb);
  finish(oA, lsA, qa);
}

// ---------------- launcher ----------------
extern "C" void kernel_launch(void* const* d_in, const int* in_sizes, int n_in,
                              void* d_out, int out_size, void* d_ws, size_t ws_size,
                              hipStream_t stream) {
  const float* x      = (const float*)d_in[0];
  const float* ln1_g  = (const float*)d_in[1];
  const float* ln1_b  = (const float*)d_in[2];
  const float* W_attn = (const float*)d_in[3];
  const float* b_attn = (const float*)d_in[4];
  const float* W_proj = (const float*)d_in[5];
  const float* b_proj = (const float*)d_in[6];
  const float* ln2_g  = (const float*)d_in[7];
  const float* ln2_b  = (const float*)d_in[8];
  const float* W_up   = (const float*)d_in[9];
  const float* b_up   = (const float*)d_in[10];
  const float* W_down = (const float*)d_in[11];
  const float* b_down = (const float*)d_in[12];
  float* out = (float*)d_out;

  char* p = (char*)d_ws;
  bf16* Wattn_b = (bf16*)p; p += (size_t)3 * D_MODEL * D_MODEL * 2;
  bf16* Wproj_b = (bf16*)p; p += (size_t)D_MODEL * D_MODEL * 2;
  bf16* Wup_b   = (bf16*)p; p += (size_t)4 * D_MODEL * D_MODEL * 2;
  bf16* Wdown_b = (bf16*)p; p += (size_t)4 * D_MODEL * D_MODEL * 2;
  bf16* h_b     = (bf16*)p; p += (size_t)NTOK * D_MODEL * 2;
  bf16* qkv_b   = (bf16*)p; p += (size_t)NTOK * 3 * D_MODEL * 2;
  bf16* o_b     = (bf16*)p; p += (size_t)NTOK * D_MODEL * 2;
  bf16* h2_b    = (bf16*)p; p += (size_t)NTOK * D_MODEL * 2;
  bf16* up_b    = (bf16*)p; p += (size_t)NTOK * 4 * D_MODEL * 2;

  {
    size_t ntot = (size_t)12 * D_MODEL * D_MODEL;
    f2bf4_kernel<<<(int)(ntot / 1024), 256, 0, stream>>>(W_attn, W_proj, W_up, W_down, Wattn_b);
  }
  ln_kernel<<<NTOK, 256, 0, stream>>>(x, ln1_g, ln1_b, h_b);
  gemm_nt<EP_BIAS_BF16><<<dim3(NTOK / 128, 3 * D_MODEL / 128), 256, 0, stream>>>(
      h_b, Wattn_b, b_attn, nullptr, qkv_b, NTOK, 3 * D_MODEL, D_MODEL);
  attn_kernel<<<dim3(16, 2 * NHEAD), 256, 0, stream>>>((const short*)qkv_b, (short*)o_b);
  gemm_nt2<EP_BIAS_RES_F32><<<dim3(NTOK / 128, D_MODEL / 64), 256, 0, stream>>>(
      o_b, Wproj_b, b_proj, x, out, NTOK, D_MODEL, D_MODEL);
  ln_kernel<<<NTOK, 256, 0, stream>>>(out, ln2_g, ln2_b, h2_b);
  gemm_nt<EP_BIAS_GELU_BF16><<<dim3(NTOK / 128, 4 * D_MODEL / 128), 256, 0, stream>>>(
      h2_b, Wup_b, b_up, nullptr, up_b, NTOK, 4 * D_MODEL, D_MODEL);
  gemm_nt2<EP_BIAS_RES_F32><<<dim3(NTOK / 128, D_MODEL / 64), 256, 0, stream>>>(
      up_b, Wdown_b, b_down, out, out, NTOK, D_MODEL, 4 * D_MODEL);
}

// Round 11
// 352.352 us; speedup vs baseline: 1.2342x; 1.2342x over previous
//
#include <hip/hip_runtime.h>
#include <hip/hip_bf16.h>

typedef __hip_bfloat16 bf16;
using bf16x8 = __attribute__((ext_vector_type(8))) short;
using bf16x4 = __attribute__((ext_vector_type(4))) short;
using f32x4  = __attribute__((ext_vector_type(4))) float;

#define D_MODEL 1024
#define SEQ     2048
#define NTOK    4096
#define NHEAD   16
#define DHEAD   64

__device__ inline f32x4 mfma16(bf16x8 a, bf16x8 b, f32x4 c) {
  return __builtin_amdgcn_mfma_f32_16x16x32_bf16(a, b, c, 0, 0, 0);
}

// 16x16x16 bf16 MFMA (K=16): A/B = 4 bf16 (2 VGPRs), k = quad*4+j
__device__ inline f32x4 mfma16k16(bf16x4 a, bf16x4 b, f32x4 c) {
#if __has_builtin(__builtin_amdgcn_mfma_f32_16x16x16bf16_1k)
  return __builtin_amdgcn_mfma_f32_16x16x16bf16_1k(a, b, c, 0, 0, 0);
#else
  f32x4 d;
  asm("v_mfma_f32_16x16x16_bf16 %0, %1, %2, %3" : "=v"(d) : "v"(a), "v"(b), "v"(c));
  return d;
#endif
}

// async global->LDS, 16B per lane, dest = wave-uniform base + lane*16
__device__ inline void glds16(const void* g, void* l) {
  __builtin_amdgcn_global_load_lds(
      (const __attribute__((address_space(1))) unsigned int*)g,
      (__attribute__((address_space(3))) unsigned int*)l, 16, 0, 0);
}

#define LGKM0_BARRIER()                                        \
  asm volatile("s_waitcnt lgkmcnt(0)" ::: "memory");           \
  asm volatile("s_barrier" ::: "memory")

// ---------------- fp32 -> bf16 convert, all 4 weights in one launch ----------
__global__ __launch_bounds__(256) void f2bf4_kernel(const float* __restrict__ s0,
                                                    const float* __restrict__ s1,
                                                    const float* __restrict__ s2,
                                                    const float* __restrict__ s3,
                                                    bf16* __restrict__ dst) {
  const size_t M1 = (size_t)D_MODEL * D_MODEL;
  size_t i = ((size_t)blockIdx.x * 256 + threadIdx.x) * 4;
  const float* s; size_t off;
  if (i < 3 * M1)      { s = s0; off = i; }
  else if (i < 4 * M1) { s = s1; off = i - 3 * M1; }
  else if (i < 8 * M1) { s = s2; off = i - 4 * M1; }
  else                 { s = s3; off = i - 8 * M1; }
  float4 v = *(const float4*)(s + off);
  dst[i + 0] = __float2bfloat16(v.x);
  dst[i + 1] = __float2bfloat16(v.y);
  dst[i + 2] = __float2bfloat16(v.z);
  dst[i + 3] = __float2bfloat16(v.w);
}

// ---------------- layernorm fp32 -> bf16 ----------------
__global__ __launch_bounds__(256) void ln_kernel(const float* __restrict__ x,
                                                 const float* __restrict__ g,
                                                 const float* __restrict__ bta,
                                                 bf16* __restrict__ out) {
  int row = blockIdx.x;
  int tid = threadIdx.x;
  const float* xr = x + (size_t)row * D_MODEL;
  float4 v = *(const float4*)(xr + tid * 4);
  float s  = v.x + v.y + v.z + v.w;
  float s2 = v.x * v.x + v.y * v.y + v.z * v.z + v.w * v.w;
  for (int o = 32; o > 0; o >>= 1) {
    s  += __shfl_down(s, o);
    s2 += __shfl_down(s2, o);
  }
  __shared__ float red[8];
  int wave = tid >> 6, lane = tid & 63;
  if (lane == 0) { red[wave] = s; red[4 + wave] = s2; }
  __syncthreads();
  s  = red[0] + red[1] + red[2] + red[3];
  s2 = red[4] + red[5] + red[6] + red[7];
  float mu  = s * (1.f / D_MODEL);
  float var = s2 * (1.f / D_MODEL) - mu * mu;
  float rs  = rsqrtf(var + 1e-5f);
  float4 gv = *(const float4*)(g + tid * 4);
  float4 bv = *(const float4*)(bta + tid * 4);
  bf16* orow = out + (size_t)row * D_MODEL + tid * 4;
  orow[0] = __float2bfloat16((v.x - mu) * rs * gv.x + bv.x);
  orow[1] = __float2bfloat16((v.y - mu) * rs * gv.y + bv.y);
  orow[2] = __float2bfloat16((v.z - mu) * rs * gv.z + bv.z);
  orow[3] = __float2bfloat16((v.w - mu) * rs * gv.w + bv.w);
}

// ---------------- epilogue helper ----------------
#define EP_BIAS_BF16      0
#define EP_BIAS_GELU_BF16 1
#define EP_BIAS_RES_F32   2

template <int EP>
__device__ inline void ep_store(void* out, const float* res, size_t off, float v) {
  if (EP == EP_BIAS_BF16) {
    ((bf16*)out)[off] = __float2bfloat16(v);
  } else if (EP == EP_BIAS_GELU_BF16) {
    float u = 0.7978845608f * (v + 0.044715f * v * v * v);
    float gl = v / (1.0f + __expf(-2.0f * u));  // 0.5v(1+tanh(u)) == v*sigmoid(2u)
    ((bf16*)out)[off] = __float2bfloat16(gl);
  } else {
    ((float*)out)[off] = res[off] + v;
  }
}

// ---------------- NT GEMM 128x128, BK=64, glds16 staging (round-6 best) ------
template <int EP>
__global__ __launch_bounds__(256, 3) void gemm_nt(const bf16* __restrict__ A,
                                                  const bf16* __restrict__ W,
                                                  const float* __restrict__ bias,
                                                  const float* res, void* out,
                                                  int M, int N, int K) {
  __shared__ short sA[128 * 64];
  __shared__ short sB[128 * 64];
  int tid  = threadIdx.x;
  int wave = tid >> 6, lane = tid & 63;
  int quad = lane >> 4, l16 = lane & 15;
  int wm = (wave >> 1) * 64, wn = (wave & 1) * 64;
  int bm = blockIdx.x * 128, bn = blockIdx.y * 128;

  int rl = lane >> 3;
  int cz = (lane & 7) ^ rl;
  const bf16* aptr[4];
  const bf16* bptr[4];
#pragma unroll
  for (int i = 0; i < 4; i++) {
    int j = wave * 4 + i;
    aptr[i] = A + (size_t)(bm + j * 8 + rl) * K + cz * 8;
    bptr[i] = W + (size_t)(bn + j * 8 + rl) * K + cz * 8;
  }

  f32x4 acc[4][4] = {};

  for (int k0 = 0; k0 < K; k0 += 64) {
    __syncthreads();
#pragma unroll
    for (int i = 0; i < 4; i++) {
      glds16(aptr[i] + k0, (char*)sA + (wave * 4 + i) * 1024);
      glds16(bptr[i] + k0, (char*)sB + (wave * 4 + i) * 1024);
    }
    __builtin_amdgcn_s_waitcnt(0);
    __syncthreads();

#pragma unroll
    for (int kk = 0; kk < 2; kk++) {
      int cq = kk * 4 + quad;
      int sw = (cq ^ (l16 & 7)) * 8;
      bf16x8 af[4], bfr[4];
#pragma unroll
      for (int t = 0; t < 4; t++) {
        af[t]  = *(const bf16x8*)&sA[(wm + t * 16 + l16) * 64 + sw];
        bfr[t] = *(const bf16x8*)&sB[(wn + t * 16 + l16) * 64 + sw];
      }
#pragma unroll
      for (int mt = 0; mt < 4; mt++)
#pragma unroll
        for (int nt = 0; nt < 4; nt++)
          acc[mt][nt] = mfma16(af[mt], bfr[nt], acc[mt][nt]);
    }
  }

#pragma unroll
  for (int mt = 0; mt < 4; mt++)
#pragma unroll
    for (int nt = 0; nt < 4; nt++) {
      int col = bn + wn + nt * 16 + l16;
      float bs = bias[col];
#pragma unroll
      for (int i = 0; i < 4; i++) {
        int row = bm + wm + mt * 16 + quad * 4 + i;
        ep_store<EP>(out, res, (size_t)row * N + col, acc[mt][nt][i] + bs);
      }
    }
}

// ---------------- NT GEMM 128x64 (N=1024 GEMMs: 512 blocks, round-6 best) ----
template <int EP>
__global__ __launch_bounds__(256, 3) void gemm_nt2(const bf16* __restrict__ A,
                                                   const bf16* __restrict__ W,
                                                   const float* __restrict__ bias,
                                                   const float* res, void* out,
                                                   int M, int N, int K) {
  __shared__ short sA[128 * 64];
  __shared__ short sB[64 * 64];
  int tid  = threadIdx.x;
  int wave = tid >> 6, lane = tid & 63;
  int quad = lane >> 4, l16 = lane & 15;
  int wm = wave * 32;
  int bm = blockIdx.x * 128, bn = blockIdx.y * 64;

  int rl = lane >> 3;
  int cz = (lane & 7) ^ rl;
  const bf16* aptr[4];
  const bf16* bptr[2];
#pragma unroll
  for (int i = 0; i < 4; i++)
    aptr[i] = A + (size_t)(bm + (wave * 4 + i) * 8 + rl) * K + cz * 8;
#pragma unroll
  for (int i = 0; i < 2; i++)
    bptr[i] = W + (size_t)(bn + (wave * 2 + i) * 8 + rl) * K + cz * 8;

  f32x4 acc[2][4] = {};

  for (int k0 = 0; k0 < K; k0 += 64) {
    __syncthreads();
#pragma unroll
    for (int i = 0; i < 4; i++)
      glds16(aptr[i] + k0, (char*)sA + (wave * 4 + i) * 1024);
#pragma unroll
    for (int i = 0; i < 2; i++)
      glds16(bptr[i] + k0, (char*)sB + (wave * 2 + i) * 1024);
    __builtin_amdgcn_s_waitcnt(0);
    __syncthreads();

#pragma unroll
    for (int kk = 0; kk < 2; kk++) {
      int cq = kk * 4 + quad;
      int sw = (cq ^ (l16 & 7)) * 8;
      bf16x8 af[2], bfr[4];
#pragma unroll
      for (int t = 0; t < 2; t++)
        af[t] = *(const bf16x8*)&sA[(wm + t * 16 + l16) * 64 + sw];
#pragma unroll
      for (int t = 0; t < 4; t++)
        bfr[t] = *(const bf16x8*)&sB[(t * 16 + l16) * 64 + sw];
#pragma unroll
      for (int mt = 0; mt < 2; mt++)
#pragma unroll
        for (int nt = 0; nt < 4; nt++)
          acc[mt][nt] = mfma16(af[mt], bfr[nt], acc[mt][nt]);
    }
  }

#pragma unroll
  for (int mt = 0; mt < 2; mt++)
#pragma unroll
    for (int nt = 0; nt < 4; nt++) {
      int col = bn + nt * 16 + l16;
      float bs = bias[col];
#pragma unroll
      for (int i = 0; i < 4; i++) {
        int row = bm + wm + mt * 16 + quad * 4 + i;
        ep_store<EP>(out, res, (size_t)row * N + col, acc[mt][nt][i] + bs);
      }
    }
}

// ---------------- flash attention (round-7 version verbatim, best: 66 us) ----
__global__ __launch_bounds__(256, 2) void attn_kernel(const short* __restrict__ qkvS,
                                                      short* __restrict__ oS) {
  int bh = blockIdx.y;
  int b = bh >> 4, h = bh & 15;
  int iq = blockIdx.x;                  // 0..15
  int qa = iq * 64, qb = (31 - iq) * 64;
  int tid = threadIdx.x, wave = tid >> 6, lane = tid & 63;
  int quad = lane >> 4, l16 = lane & 15;
  const int RS = 3 * D_MODEL;
  const short* base = qkvS + (size_t)b * SEQ * RS;
  const int koff = D_MODEL + h * 64, voff = 2 * D_MODEL + h * 64, qoff = h * 64;
  const float c2 = 0.1803368801f;  // log2(e)/8

  __shared__ short sK[64 * 64];
  __shared__ short sV[64 * 64];

  int rl = lane >> 3, cz = (lane & 7) ^ rl;
  int vkr = tid >> 3, vd0 = (tid & 7) * 8;
  int vb7 = tid & 7;
  int kv3 = vkr & 3;
  int c4lo = vkr >> 2, c4hi = c4lo + 8;
  int xpar = (c4lo & 1) << 3;

  int qrA = qa + wave * 16 + l16, qrB = qb + wave * 16 + l16;
  bf16x8 qA0 = *(const bf16x8*)&base[(size_t)qrA * RS + qoff + quad * 8];
  bf16x8 qA1 = *(const bf16x8*)&base[(size_t)qrA * RS + qoff + 32 + quad * 8];
  bf16x8 qB0 = *(const bf16x8*)&base[(size_t)qrB * RS + qoff + quad * 8];
  bf16x8 qB1 = *(const bf16x8*)&base[(size_t)qrB * RS + qoff + 32 + quad * 8];

  f32x4 oA[4] = {}, oB[4] = {};
  float lsA = 0.f, lsB = 0.f;
  int ntile = 32 - iq;

  bf16x8 kc0, kc1, vc0, vc1;
  {
    const short* kp = &base[(size_t)(wave * 16 + rl) * RS + koff + cz * 8];
    kc0 = *(const bf16x8*)kp;
    kc1 = *(const bf16x8*)(kp + (size_t)8 * RS);
    const short* vp = &base[(size_t)vkr * RS + voff + vd0];
    vc0 = *(const bf16x8*)vp;
    vc1 = *(const bf16x8*)(vp + (size_t)32 * RS);
  }

  for (int t = 0; t < ntile; t++) {
    int kv0 = t * 64;
    LGKM0_BARRIER();   // prev tile's LDS reads done (no vmcnt drain)

    bf16x8 kn0, kn1, vn0, vn1;
    bool more = (t + 1 < ntile);
    if (more) {
      int kvn = kv0 + 64;
      const short* kp = &base[(size_t)(kvn + wave * 16 + rl) * RS + koff + cz * 8];
      kn0 = *(const bf16x8*)kp;
      kn1 = *(const bf16x8*)(kp + (size_t)8 * RS);
      const short* vp = &base[(size_t)(kvn + vkr) * RS + voff + vd0];
      vn0 = *(const bf16x8*)vp;
      vn1 = *(const bf16x8*)(vp + (size_t)32 * RS);
    }

    *(bf16x8*)&sK[(wave * 2 + 0) * 512 + lane * 8] = kc0;
    *(bf16x8*)&sK[(wave * 2 + 1) * 512 + lane * 8] = kc1;
#pragma unroll
    for (int j = 0; j < 8; j++)
      sV[c4lo * 256 + (vb7 | ((j << 3) ^ xpar)) * 4 + kv3] = vc0[j];
#pragma unroll
    for (int j = 0; j < 8; j++)
      sV[c4hi * 256 + (vb7 | ((j << 3) ^ xpar)) * 4 + kv3] = vc1[j];

    LGKM0_BARRIER();   // stage visible

    bool doA = (t <= iq);
    int xk = l16 & 7;
    f32x4 stB[4], stA[4];
#pragma unroll
    for (int t16 = 0; t16 < 4; t16++) {
      bf16x8 kf0 = *(const bf16x8*)&sK[(t16 * 16 + l16) * 64 + ((quad ^ xk) * 8)];
      bf16x8 kf1 = *(const bf16x8*)&sK[(t16 * 16 + l16) * 64 + (((quad + 4) ^ xk) * 8)];
      f32x4 z = {};
      z = mfma16(kf0, qB0, z);
      stB[t16] = mfma16(kf1, qB1, z);
      if (doA) {
        f32x4 za = {};
        za = mfma16(kf0, qA0, za);
        stA[t16] = mfma16(kf1, qA1, za);
      }
    }

    auto ptail = [&](const f32x4* st, f32x4* oo, float& ls, bool diag, int qg) {
#pragma unroll
      for (int t16 = 0; t16 < 4; t16++) {
        bf16x4 pf;
        int kvb = kv0 + t16 * 16 + quad * 4;
#pragma unroll
        for (int e = 0; e < 4; e++) {
          float p = exp2f(fminf(st[t16][e] * c2, 30.f));
          if (diag && (kvb + e > qg)) p = 0.f;
          ls += p;
          pf[e] = __builtin_bit_cast(short, __float2bfloat16(p));
        }
        int c4r = t16 * 4 + quad;
        int xr = (c4r & 1) << 3;
#pragma unroll
        for (int dt = 0; dt < 4; dt++) {
          int pr = (dt * 16 + l16) ^ xr;
          bf16x4 vb = *(const bf16x4*)&sV[c4r * 256 + pr * 4];
          oo[dt] = mfma16k16(pf, vb, oo[dt]);
        }
      }
    };

    ptail(stB, oB, lsB, t == ntile - 1, qrB);
    if (doA) ptail(stA, oA, lsA, t == iq, qrA);

    if (more) { kc0 = kn0; kc1 = kn1; vc0 = vn0; vc1 = vn1; }
  }

  auto finish = [&](f32x4* oo, float ls, int q0p) {
    ls += __shfl_xor(ls, 16);
    ls += __shfl_xor(ls, 32);
    float inv[4];
#pragma unroll
    for (int e = 0; e < 4; e++) inv[e] = 1.0f / __shfl(ls, quad * 4 + e);
    int sigbase = ((l16 & 7) << 3) | (l16 >> 3);   // sigma(dt,l16) = sigbase + dt*2
#pragma unroll
    for (int dt = 0; dt < 4; dt++)
#pragma unroll
      for (int e = 0; e < 4; e++) {
        int row = q0p + wave * 16 + quad * 4 + e;
        oS[((size_t)b * SEQ + row) * D_MODEL + qoff + sigbase + dt * 2] =
            __builtin_bit_cast(short, __float2bfloat16(oo[dt][e] * inv[e]));
      }
  };
  finish(oB, lsB, qb);
  finish(oA, lsA, qa);
}

// ---------------- launcher ----------------
extern "C" void kernel_launch(void* const* d_in, const int* in_sizes, int n_in,
                              void* d_out, int out_size, void* d_ws, size_t ws_size,
                              hipStream_t stream) {
  const float* x      = (const float*)d_in[0];
  const float* ln1_g  = (const float*)d_in[1];
  const float* ln1_b  = (const float*)d_in[2];
  const float* W_attn = (const float*)d_in[3];
  const float* b_attn = (const float*)d_in[4];
  const float* W_proj = (const float*)d_in[5];
  const float* b_proj = (const float*)d_in[6];
  const float* ln2_g  = (const float*)d_in[7];
  const float* ln2_b  = (const float*)d_in[8];
  const float* W_up   = (const float*)d_in[9];
  const float* b_up   = (const float*)d_in[10];
  const float* W_down = (const float*)d_in[11];
  const float* b_down = (const float*)d_in[12];
  float* out = (float*)d_out;

  char* p = (char*)d_ws;
  bf16* Wattn_b = (bf16*)p; p += (size_t)3 * D_MODEL * D_MODEL * 2;
  bf16* Wproj_b = (bf16*)p; p += (size_t)D_MODEL * D_MODEL * 2;
  bf16* Wup_b   = (bf16*)p; p += (size_t)4 * D_MODEL * D_MODEL * 2;
  bf16* Wdown_b = (bf16*)p; p += (size_t)4 * D_MODEL * D_MODEL * 2;
  bf16* h_b     = (bf16*)p; p += (size_t)NTOK * D_MODEL * 2;
  bf16* qkv_b   = (bf16*)p; p += (size_t)NTOK * 3 * D_MODEL * 2;
  bf16* o_b     = (bf16*)p; p += (size_t)NTOK * D_MODEL * 2;
  bf16* h2_b    = (bf16*)p; p += (size_t)NTOK * D_MODEL * 2;
  bf16* up_b    = (bf16*)p; p += (size_t)NTOK * 4 * D_MODEL * 2;

  {
    size_t ntot = (size_t)12 * D_MODEL * D_MODEL;
    f2bf4_kernel<<<(int)(ntot / 1024), 256, 0, stream>>>(W_attn, W_proj, W_up, W_down, Wattn_b);
  }
  ln_kernel<<<NTOK, 256, 0, stream>>>(x, ln1_g, ln1_b, h_b);
  gemm_nt<EP_BIAS_BF16><<<dim3(NTOK / 128, 3 * D_MODEL / 128), 256, 0, stream>>>(
      h_b, Wattn_b, b_attn, nullptr, qkv_b, NTOK, 3 * D_MODEL, D_MODEL);
  attn_kernel<<<dim3(16, 2 * NHEAD), 256, 0, stream>>>((const short*)qkv_b, (short*)o_b);
  gemm_nt2<EP_BIAS_RES_F32><<<dim3(NTOK / 128, D_MODEL / 64), 256, 0, stream>>>(
      o_b, Wproj_b, b_proj, x, out, NTOK, D_MODEL, D_MODEL);
  ln_kernel<<<NTOK, 256, 0, stream>>>(out, ln2_g, ln2_b, h2_b);
  gemm_nt<EP_BIAS_GELU_BF16><<<dim3(NTOK / 128, 4 * D_MODEL / 128), 256, 0, stream>>>(
      h2_b, Wup_b, b_up, nullptr, up_b, NTOK, 4 * D_MODEL, D_MODEL);
  gemm_nt2<EP_BIAS_RES_F32><<<dim3(NTOK / 128, D_MODEL / 64), 256, 0, stream>>>(
      up_b, Wdown_b, b_down, out, out, NTOK, D_MODEL, 4 * D_MODEL);
}